// Round 1
// baseline (2870.095 us; speedup 1.0000x reference)
//
#include <hip/hip_runtime.h>
#include <hip/hip_bf16.h>
#include <math.h>

#define BDIM 384
#define HEADS 8
#define HD 48
#define HID 1536
#define BB 32
#define HH 56
#define WW 56
#define NN 3136            // 56*56
#define MTOT (BB*NN)       // 100352

typedef unsigned short ushort_t;
typedef __attribute__((ext_vector_type(8))) short short8;   // 8 x bf16 (4 VGPRs)
typedef __attribute__((ext_vector_type(4))) float floatx4;  // 4 x f32 acc

__device__ inline float bf2f(ushort_t u){ return __uint_as_float(((unsigned)u)<<16); }
__device__ inline ushort_t f2bf(float f){
  unsigned u = __float_as_uint(f);
  u += 0x7fff + ((u>>16)&1);   // round-to-nearest-even
  return (ushort_t)(u>>16);
}

// ---------------- weight fp32 -> bf16 ----------------
__global__ void convert_bf16_kernel(const float* __restrict__ in, ushort_t* __restrict__ out, int n){
  int i = blockIdx.x*256 + threadIdx.x;
  if (i < n) out[i] = f2bf(in[i]);
}

// ---------------- LN stats helper (384 threads = 6 waves) ----------------
__device__ inline void ln_stats(float v, float* red, float& mean, float& rstd){
  int lane = threadIdx.x & 63, wid = threadIdx.x >> 6;
  float s = v, q = v*v;
  #pragma unroll
  for (int off = 32; off > 0; off >>= 1){
    s += __shfl_down(s, off);
    q += __shfl_down(q, off);
  }
  if (lane == 0){ red[wid] = s; red[6+wid] = q; }
  __syncthreads();
  float ts = 0.f, tq = 0.f;
  #pragma unroll
  for (int i = 0; i < 6; ++i){ ts += red[i]; tq += red[6+i]; }
  mean = ts * (1.f/384.f);
  float var = tq * (1.f/384.f) - mean*mean;
  rstd = rsqrtf(var + 1e-5f);
}

// ---------------- CPE depthwise 3x3 conv + residual + LN1 ----------------
// one block per token (b,n); 384 threads = one channel each
__global__ __launch_bounds__(384)
void cpe_ln1_kernel(const float* __restrict__ x, const float* __restrict__ cw,
                    const float* __restrict__ cb, const float* __restrict__ lw,
                    const float* __restrict__ lb, float* __restrict__ x1out,
                    ushort_t* __restrict__ cur){
  __shared__ float red[12];
  int bn = blockIdx.x;
  int b = bn / NN, n = bn % NN;
  int h = n / WW, w = n % WW;
  int c = threadIdx.x;
  const float* xb = x + (size_t)b*NN*BDIM;
  float conv = cb[c];
  #pragma unroll
  for (int dh = -1; dh <= 1; ++dh){
    int hh = h + dh; if ((unsigned)hh >= HH) continue;
    #pragma unroll
    for (int dw = -1; dw <= 1; ++dw){
      int ww2 = w + dw; if ((unsigned)ww2 >= WW) continue;
      conv += xb[(size_t)(hh*WW + ww2)*BDIM + c] * cw[c*9 + (dh+1)*3 + (dw+1)];
    }
  }
  float x1 = xb[(size_t)n*BDIM + c] + conv;
  x1out[(size_t)bn*BDIM + c] = x1;
  float mean, rstd;
  ln_stats(x1, red, mean, rstd);
  cur[(size_t)bn*BDIM + c] = f2bf((x1 - mean)*rstd*lw[c] + lb[c]);
}

// ---------------- plain LN (x fp32 -> bf16 normalized) ----------------
__global__ __launch_bounds__(384)
void ln_kernel(const float* __restrict__ xin, const float* __restrict__ lw,
               const float* __restrict__ lb, ushort_t* __restrict__ outb){
  __shared__ float red[12];
  size_t bn = blockIdx.x;
  int c = threadIdx.x;
  float v = xin[bn*BDIM + c];
  float mean, rstd;
  ln_stats(v, red, mean, rstd);
  outb[bn*BDIM + c] = f2bf((v - mean)*rstd*lw[c] + lb[c]);
}

// ---------------- bf16 MFMA GEMM: C[M,Ncols] = A[M,K] @ Bw[Ncols,K]^T + bias ----------------
// BM=BN=128, BK=32; 256 threads = 4 waves in 2x2; each wave: 4x4 tiles of 16x16
// EP: 0 = qkv (relu cols<768, bf16 out), 1 = fc1 (exact gelu, bf16 out), 2 = +resid, f32 out
template<int EP>
__global__ __launch_bounds__(256)
void gemm_kernel(const ushort_t* __restrict__ A, const ushort_t* __restrict__ Bw,
                 const float* __restrict__ bias, const float* __restrict__ resid,
                 void* __restrict__ outp, int Ncols, int K){
  __shared__ __align__(16) ushort_t As[128*32];
  __shared__ __align__(16) ushort_t Bs[128*32];
  const int t = threadIdx.x;
  const int lane = t & 63, wave = t >> 6;
  const int wm = wave >> 1, wn = wave & 1;
  const size_t m0 = (size_t)blockIdx.y * 128;
  const int n0 = blockIdx.x * 128;
  const int lrow = lane & 15, lk = (lane >> 4) << 3;  // quad*8
  floatx4 zero4 = {0.f, 0.f, 0.f, 0.f};
  floatx4 acc[4][4];
  #pragma unroll
  for (int i = 0; i < 4; ++i)
    #pragma unroll
    for (int j = 0; j < 4; ++j) acc[i][j] = zero4;

  for (int k0 = 0; k0 < K; k0 += 32){
    #pragma unroll
    for (int l = 0; l < 2; ++l){
      int idx = t + l*256;              // 0..511
      int row = idx >> 2;               // 0..127
      int ko  = (idx & 3) << 3;         // 0,8,16,24
      *(uint4*)&As[row*32 + ko] = *(const uint4*)&A[(m0 + row)*K + (k0 + ko)];
      *(uint4*)&Bs[row*32 + ko] = *(const uint4*)&Bw[(size_t)(n0 + row)*K + (k0 + ko)];
    }
    __syncthreads();
    short8 af[4], bfr[4];
    #pragma unroll
    for (int i = 0; i < 4; ++i) af[i]  = *(const short8*)&As[(wm*64 + i*16 + lrow)*32 + lk];
    #pragma unroll
    for (int j = 0; j < 4; ++j) bfr[j] = *(const short8*)&Bs[(wn*64 + j*16 + lrow)*32 + lk];
    #pragma unroll
    for (int i = 0; i < 4; ++i)
      #pragma unroll
      for (int j = 0; j < 4; ++j)
        acc[i][j] = __builtin_amdgcn_mfma_f32_16x16x32_bf16(af[i], bfr[j], acc[i][j], 0, 0, 0);
    __syncthreads();
  }

  const int quad = lane >> 4;
  #pragma unroll
  for (int i = 0; i < 4; ++i){
    #pragma unroll
    for (int j = 0; j < 4; ++j){
      int gn = n0 + wn*64 + j*16 + lrow;
      float bv = bias[gn];
      #pragma unroll
      for (int r = 0; r < 4; ++r){
        size_t gm = m0 + wm*64 + i*16 + quad*4 + r;
        float v = acc[i][j][r] + bv;
        if constexpr (EP == 0){           // qkv: relu on q,k cols
          if (gn < 768) v = fmaxf(v, 0.f);
          ((ushort_t*)outp)[gm*Ncols + gn] = f2bf(v);
        } else if constexpr (EP == 1){    // fc1: exact gelu
          v = 0.5f*v*(1.f + erff(v*0.70710678118f));
          ((ushort_t*)outp)[gm*Ncols + gn] = f2bf(v);
        } else {                          // proj / fc2: + fp32 residual, fp32 out
          ((float*)outp)[gm*Ncols + gn] = v + resid[gm*Ncols + gn];
        }
      }
    }
  }
}

// ---------------- per-(b,h): kv[48,48] = sum_n k^T v * temp ; ksum[48] ----------------
__global__ __launch_bounds__(256)
void kv_kernel(const ushort_t* __restrict__ qkv, const float* __restrict__ temp,
               float* __restrict__ kv_out, float* __restrict__ ksum_out){
  int bh = blockIdx.x; int b = bh >> 3, h = bh & 7;
  int t = threadIdx.x;
  __shared__ ushort_t kT[64*48];
  __shared__ ushort_t vT[64*48];
  const ushort_t* kbase = qkv + (size_t)b*NN*1152 + 384 + h*48;  // k cols; v = +384
  float acc[9];
  #pragma unroll
  for (int r = 0; r < 9; ++r) acc[r] = 0.f;
  int d0 = (t >> 4) * 3;   // 16 groups of 3 rows
  int e0 = (t & 15) * 3;   // 16 groups of 3 cols
  float ks = 0.f;
  for (int n0 = 0; n0 < NN; n0 += 64){
    for (int e = t; e < 3072; e += 256){
      int nl = e / 48, d = e - nl*48;
      size_t rowoff = (size_t)(n0 + nl)*1152;
      kT[e] = kbase[rowoff + d];
      vT[e] = kbase[rowoff + 384 + d];
    }
    __syncthreads();
    #pragma unroll 4
    for (int nl = 0; nl < 64; ++nl){
      float kd0 = bf2f(kT[nl*48+d0]), kd1 = bf2f(kT[nl*48+d0+1]), kd2 = bf2f(kT[nl*48+d0+2]);
      float ve0 = bf2f(vT[nl*48+e0]), ve1 = bf2f(vT[nl*48+e0+1]), ve2 = bf2f(vT[nl*48+e0+2]);
      acc[0] += kd0*ve0; acc[1] += kd0*ve1; acc[2] += kd0*ve2;
      acc[3] += kd1*ve0; acc[4] += kd1*ve1; acc[5] += kd1*ve2;
      acc[6] += kd2*ve0; acc[7] += kd2*ve1; acc[8] += kd2*ve2;
    }
    if (t < 48){
      float s = 0.f;
      for (int nl = 0; nl < 64; ++nl) s += bf2f(kT[nl*48 + t]);
      ks += s;
    }
    __syncthreads();
  }
  float tf = temp[h];
  float* kvb = kv_out + (size_t)bh*HD*HD;
  #pragma unroll
  for (int r = 0; r < 9; ++r){
    int d = d0 + r/3, e = e0 + r%3;
    kvb[d*48 + e] = acc[r] * tf;
  }
  if (t < 48) ksum_out[bh*48 + t] = ks;
}

// ---------------- attn_out[b,n,h,:] = (q @ kv) / max(q . ksum, 100) ----------------
__global__ __launch_bounds__(256)
void attn_kernel(const ushort_t* __restrict__ qkv, const float* __restrict__ kv,
                 const float* __restrict__ ksum, ushort_t* __restrict__ attn_out){
  int bh = blockIdx.x; int b = bh >> 3, h = bh & 7;
  int chunk = blockIdx.y;  // 0..6, each covers 7 stages of 64 tokens (49 total)
  int t = threadIdx.x;
  __shared__ float kvs[48*48];
  __shared__ float kss[48];
  __shared__ ushort_t qT[64*48];
  __shared__ float den[64];
  for (int i = t; i < 2304; i += 256) kvs[i] = kv[(size_t)bh*2304 + i];
  if (t < 48) kss[t] = ksum[bh*48 + t];
  __syncthreads();
  const ushort_t* qbase = qkv + (size_t)b*NN*1152 + h*48;
  ushort_t* obase = attn_out + (size_t)b*NN*BDIM + h*48;
  for (int s = 0; s < 7; ++s){
    int n0 = (chunk*7 + s)*64;
    for (int e = t; e < 3072; e += 256){
      int nl = e / 48, d = e - nl*48;
      qT[e] = qbase[(size_t)(n0 + nl)*1152 + d];
    }
    __syncthreads();
    if (t < 64){
      float sdot = 0.f;
      #pragma unroll 8
      for (int d = 0; d < 48; ++d) sdot += bf2f(qT[t*48 + d]) * kss[d];
      den[t] = fmaxf(sdot, 100.f);
    }
    __syncthreads();
    #pragma unroll
    for (int r = 0; r < 12; ++r){
      int o = t + 256*r;
      int nl = o / 48, e = o - nl*48;
      float sv = 0.f;
      #pragma unroll 8
      for (int d = 0; d < 48; ++d) sv += bf2f(qT[nl*48 + d]) * kvs[d*48 + e];
      obase[(size_t)(n0 + nl)*BDIM + e] = f2bf(sv / den[nl]);
    }
    __syncthreads();
  }
}

extern "C" void kernel_launch(void* const* d_in, const int* in_sizes, int n_in,
                              void* d_out, int out_size, void* d_ws, size_t ws_size,
                              hipStream_t stream){
  const float* x     = (const float*)d_in[0];
  const float* cpe_w = (const float*)d_in[3];
  const float* cpe_b = (const float*)d_in[4];
  const float* ln1_w = (const float*)d_in[5];
  const float* ln1_b = (const float*)d_in[6];
  const float* qkv_w = (const float*)d_in[7];
  const float* qkv_b = (const float*)d_in[8];
  const float* temp  = (const float*)d_in[9];
  const float* proj_w= (const float*)d_in[10];
  const float* proj_b= (const float*)d_in[11];
  const float* ln2_w = (const float*)d_in[12];
  const float* ln2_b = (const float*)d_in[13];
  const float* fc1_w = (const float*)d_in[14];
  const float* fc1_b = (const float*)d_in[15];
  const float* fc2_w = (const float*)d_in[16];
  const float* fc2_b = (const float*)d_in[17];
  float* out = (float*)d_out;

  char* ws = (char*)d_ws;
  size_t off = 0;
  auto alloc = [&](size_t bytes) -> void* {
    void* p = ws + off;
    off += (bytes + 255) & ~(size_t)255;
    return p;
  };
  ushort_t* cur  = (ushort_t*)alloc((size_t)MTOT*BDIM*2);        // LN out / attn_out (bf16)
  ushort_t* big  = (ushort_t*)alloc((size_t)MTOT*HID*2);         // qkv [M,1152] then h [M,1536]
  float*    kv   = (float*)   alloc((size_t)BB*HEADS*HD*HD*4);
  float*    ksum = (float*)   alloc((size_t)BB*HEADS*HD*4);
  ushort_t* wq = (ushort_t*)alloc((size_t)3*BDIM*BDIM*2);
  ushort_t* wp = (ushort_t*)alloc((size_t)BDIM*BDIM*2);
  ushort_t* w1 = (ushort_t*)alloc((size_t)HID*BDIM*2);
  ushort_t* w2 = (ushort_t*)alloc((size_t)BDIM*HID*2);

  // weight converts (cheap, ~2.4M elems total)
  convert_bf16_kernel<<<(3*BDIM*BDIM + 255)/256, 256, 0, stream>>>(qkv_w, wq, 3*BDIM*BDIM);
  convert_bf16_kernel<<<(BDIM*BDIM + 255)/256, 256, 0, stream>>>(proj_w, wp, BDIM*BDIM);
  convert_bf16_kernel<<<(HID*BDIM + 255)/256, 256, 0, stream>>>(fc1_w, w1, HID*BDIM);
  convert_bf16_kernel<<<(BDIM*HID + 255)/256, 256, 0, stream>>>(fc2_w, w2, BDIM*HID);

  // x1 = x + CPE(x) -> d_out (fp32 trunk); cur = LN1(x1) bf16
  cpe_ln1_kernel<<<MTOT, 384, 0, stream>>>(x, cpe_w, cpe_b, ln1_w, ln1_b, out, cur);
  // qkv = cur @ qkv_w^T + b ; relu(q,k) -> big [M,1152] bf16
  gemm_kernel<0><<<dim3(9, 784), 256, 0, stream>>>(cur, wq, qkv_b, nullptr, big, 1152, BDIM);
  // kv, ksum per (b,h)
  kv_kernel<<<BB*HEADS, 256, 0, stream>>>(big, temp, kv, ksum);
  // attn_out -> cur [M,384] bf16
  attn_kernel<<<dim3(BB*HEADS, 7), 256, 0, stream>>>(big, kv, ksum, cur);
  // x2 = x1 + attn @ proj_w^T + b -> d_out fp32
  gemm_kernel<2><<<dim3(3, 784), 256, 0, stream>>>(cur, wp, proj_b, out, out, BDIM, BDIM);
  // cur = LN2(x2) bf16
  ln_kernel<<<MTOT, 384, 0, stream>>>(out, ln2_w, ln2_b, cur);
  // h = gelu(cur @ fc1_w^T + b) -> big [M,1536] bf16
  gemm_kernel<1><<<dim3(12, 784), 256, 0, stream>>>(cur, w1, fc1_b, nullptr, big, HID, BDIM);
  // out = x2 + h @ fc2_w^T + b -> d_out fp32
  gemm_kernel<2><<<dim3(3, 784), 256, 0, stream>>>(big, w2, fc2_b, out, out, BDIM, HID);
}

// Round 2
// 1721.012 us; speedup vs baseline: 1.6677x; 1.6677x over previous
//
#include <hip/hip_runtime.h>
#include <hip/hip_bf16.h>
#include <math.h>

#define BDIM 384
#define HEADS 8
#define HD 48
#define HID 1536
#define BB 32
#define HH 56
#define WW 56
#define NN 3136            // 56*56
#define MTOT (BB*NN)       // 100352

typedef unsigned short ushort_t;
typedef __attribute__((ext_vector_type(8))) short short8;   // 8 x bf16 (4 VGPRs)
typedef __attribute__((ext_vector_type(4))) float floatx4;  // 4 x f32 acc

__device__ inline float bf2f(ushort_t u){ return __uint_as_float(((unsigned)u)<<16); }
__device__ inline ushort_t f2bf(float f){
  unsigned u = __float_as_uint(f);
  u += 0x7fff + ((u>>16)&1);   // round-to-nearest-even
  return (ushort_t)(u>>16);
}

// ---------------- weight fp32 -> bf16 ----------------
__global__ void convert_bf16_kernel(const float* __restrict__ in, ushort_t* __restrict__ out, int n){
  int i = blockIdx.x*256 + threadIdx.x;
  if (i < n) out[i] = f2bf(in[i]);
}

// ---------------- LN stats helper (384 threads = 6 waves) ----------------
__device__ inline void ln_stats(float v, float* red, float& mean, float& rstd){
  int lane = threadIdx.x & 63, wid = threadIdx.x >> 6;
  float s = v, q = v*v;
  #pragma unroll
  for (int off = 32; off > 0; off >>= 1){
    s += __shfl_down(s, off);
    q += __shfl_down(q, off);
  }
  if (lane == 0){ red[wid] = s; red[6+wid] = q; }
  __syncthreads();
  float ts = 0.f, tq = 0.f;
  #pragma unroll
  for (int i = 0; i < 6; ++i){ ts += red[i]; tq += red[6+i]; }
  mean = ts * (1.f/384.f);
  float var = tq * (1.f/384.f) - mean*mean;
  rstd = rsqrtf(var + 1e-5f);
}

// ---------------- CPE depthwise 3x3 conv + residual + LN1 ----------------
__global__ __launch_bounds__(384)
void cpe_ln1_kernel(const float* __restrict__ x, const float* __restrict__ cw,
                    const float* __restrict__ cb, const float* __restrict__ lw,
                    const float* __restrict__ lb, float* __restrict__ x1out,
                    ushort_t* __restrict__ cur){
  __shared__ float red[12];
  int bn = blockIdx.x;
  int b = bn / NN, n = bn % NN;
  int h = n / WW, w = n % WW;
  int c = threadIdx.x;
  const float* xb = x + (size_t)b*NN*BDIM;
  float conv = cb[c];
  #pragma unroll
  for (int dh = -1; dh <= 1; ++dh){
    int hh = h + dh; if ((unsigned)hh >= HH) continue;
    #pragma unroll
    for (int dw = -1; dw <= 1; ++dw){
      int ww2 = w + dw; if ((unsigned)ww2 >= WW) continue;
      conv += xb[(size_t)(hh*WW + ww2)*BDIM + c] * cw[c*9 + (dh+1)*3 + (dw+1)];
    }
  }
  float x1 = xb[(size_t)n*BDIM + c] + conv;
  x1out[(size_t)bn*BDIM + c] = x1;
  float mean, rstd;
  ln_stats(x1, red, mean, rstd);
  cur[(size_t)bn*BDIM + c] = f2bf((x1 - mean)*rstd*lw[c] + lb[c]);
}

// ---------------- plain LN ----------------
__global__ __launch_bounds__(384)
void ln_kernel(const float* __restrict__ xin, const float* __restrict__ lw,
               const float* __restrict__ lb, ushort_t* __restrict__ outb){
  __shared__ float red[12];
  size_t bn = blockIdx.x;
  int c = threadIdx.x;
  float v = xin[bn*BDIM + c];
  float mean, rstd;
  ln_stats(v, red, mean, rstd);
  outb[bn*BDIM + c] = f2bf((v - mean)*rstd*lw[c] + lb[c]);
}

// ---------------- bf16 MFMA GEMM (unchanged from R1) ----------------
template<int EP>
__global__ __launch_bounds__(256)
void gemm_kernel(const ushort_t* __restrict__ A, const ushort_t* __restrict__ Bw,
                 const float* __restrict__ bias, const float* __restrict__ resid,
                 void* __restrict__ outp, int Ncols, int K){
  __shared__ __align__(16) ushort_t As[128*32];
  __shared__ __align__(16) ushort_t Bs[128*32];
  const int t = threadIdx.x;
  const int lane = t & 63, wave = t >> 6;
  const int wm = wave >> 1, wn = wave & 1;
  const size_t m0 = (size_t)blockIdx.y * 128;
  const int n0 = blockIdx.x * 128;
  const int lrow = lane & 15, lk = (lane >> 4) << 3;
  floatx4 zero4 = {0.f, 0.f, 0.f, 0.f};
  floatx4 acc[4][4];
  #pragma unroll
  for (int i = 0; i < 4; ++i)
    #pragma unroll
    for (int j = 0; j < 4; ++j) acc[i][j] = zero4;

  for (int k0 = 0; k0 < K; k0 += 32){
    #pragma unroll
    for (int l = 0; l < 2; ++l){
      int idx = t + l*256;
      int row = idx >> 2;
      int ko  = (idx & 3) << 3;
      *(uint4*)&As[row*32 + ko] = *(const uint4*)&A[(m0 + row)*K + (k0 + ko)];
      *(uint4*)&Bs[row*32 + ko] = *(const uint4*)&Bw[(size_t)(n0 + row)*K + (k0 + ko)];
    }
    __syncthreads();
    short8 af[4], bfr[4];
    #pragma unroll
    for (int i = 0; i < 4; ++i) af[i]  = *(const short8*)&As[(wm*64 + i*16 + lrow)*32 + lk];
    #pragma unroll
    for (int j = 0; j < 4; ++j) bfr[j] = *(const short8*)&Bs[(wn*64 + j*16 + lrow)*32 + lk];
    #pragma unroll
    for (int i = 0; i < 4; ++i)
      #pragma unroll
      for (int j = 0; j < 4; ++j)
        acc[i][j] = __builtin_amdgcn_mfma_f32_16x16x32_bf16(af[i], bfr[j], acc[i][j], 0, 0, 0);
    __syncthreads();
  }

  const int quad = lane >> 4;
  #pragma unroll
  for (int i = 0; i < 4; ++i){
    #pragma unroll
    for (int j = 0; j < 4; ++j){
      int gn = n0 + wn*64 + j*16 + lrow;
      float bv = bias[gn];
      #pragma unroll
      for (int r = 0; r < 4; ++r){
        size_t gm = m0 + wm*64 + i*16 + quad*4 + r;
        float v = acc[i][j][r] + bv;
        if constexpr (EP == 0){
          if (gn < 768) v = fmaxf(v, 0.f);
          ((ushort_t*)outp)[gm*Ncols + gn] = f2bf(v);
        } else if constexpr (EP == 1){
          v = 0.5f*v*(1.f + erff(v*0.70710678118f));
          ((ushort_t*)outp)[gm*Ncols + gn] = f2bf(v);
        } else {
          ((float*)outp)[gm*Ncols + gn] = v + resid[gm*Ncols + gn];
        }
      }
    }
  }
}

// ---------------- kv via MFMA: kvT[e*48+d] += sum_n k[n,d] v[n,e]; ksum[d] += sum_n k[n,d] ----------------
// grid (256 bh, 7 chunks of 448 tokens); block 256 = 4 waves
__global__ __launch_bounds__(256)
void kv_mfma_kernel(const ushort_t* __restrict__ qkv, float* __restrict__ kvT_out,
                    float* __restrict__ ksum_out){
  __shared__ __align__(16) ushort_t smem[2*48*72];   // kT [48][72], vT [48][72]
  ushort_t* kT = smem;
  ushort_t* vT = smem + 48*72;
  int bh = blockIdx.x, b = bh >> 3, h = bh & 7;
  int chunk = blockIdx.y;
  int t = threadIdx.x, lane = t & 63, wave = t >> 6;
  int lrow = lane & 15, quad = lane >> 4;
  const ushort_t* kb = qkv + (size_t)b*NN*1152 + 384 + h*48;
  const ushort_t* vb = kb + 384;
  floatx4 acc[9];
  #pragma unroll
  for (int i = 0; i < 9; ++i) acc[i] = (floatx4){0.f,0.f,0.f,0.f};
  float ks = 0.f;

  for (int s = 0; s < 7; ++s){
    int n0 = chunk*448 + s*64;
    // stage 64 tokens of k and v, transposed, into LDS
    #pragma unroll
    for (int p = 0; p < 3; ++p){
      int u = t + p*256;              // 0..767
      int arr = u / 384;              // 0=k, 1=v (wave-uniform)
      int r = u - arr*384;
      int d8 = r >> 6;                // 0..5
      int nl = r & 63;                // = lane
      const ushort_t* src = (arr ? vb : kb) + (size_t)(n0 + nl)*1152 + d8*8;
      ushort_t* dst = arr ? vT : kT;
      uint4 val = *(const uint4*)src;
      ushort_t tmp[8];
      *(uint4*)tmp = val;
      #pragma unroll
      for (int j = 0; j < 8; ++j) dst[(d8*8 + j)*72 + nl] = tmp[j];
    }
    __syncthreads();
    // stage s holds K-steps 2s (tokens 0-31) and 2s+1 (32-63); waves 0,1 take even stages, 2,3 odd
    if ((wave >> 1) == (s & 1)){
      int kloc = (wave & 1) * 32;
      short8 af[3], bfv[3];
      #pragma unroll
      for (int i = 0; i < 3; ++i) af[i]  = *(const short8*)&kT[(i*16 + lrow)*72 + kloc + quad*8];
      #pragma unroll
      for (int j = 0; j < 3; ++j) bfv[j] = *(const short8*)&vT[(j*16 + lrow)*72 + kloc + quad*8];
      #pragma unroll
      for (int i = 0; i < 3; ++i)
        #pragma unroll
        for (int j = 0; j < 3; ++j)
          acc[i*3+j] = __builtin_amdgcn_mfma_f32_16x16x32_bf16(af[i], bfv[j], acc[i*3+j], 0, 0, 0);
    }
    if (wave == 3 && lane < 48){     // ksum for this stage
      float s2 = 0.f;
      #pragma unroll
      for (int q8 = 0; q8 < 8; ++q8){
        short8 kk = *(const short8*)&kT[lane*72 + q8*8];
        #pragma unroll
        for (int j = 0; j < 8; ++j) s2 += bf2f((ushort_t)kk[j]);
      }
      ks += s2;
    }
    __syncthreads();
  }

  // cross-wave reduce via LDS (reuse smem as float buffer, 2304 floats needed <= 3456 avail)
  float* F = (float*)smem;
  #define DUMP(W) if (wave == (W)){ _Pragma("unroll") for (int ti = 0; ti < 9; ++ti){ _Pragma("unroll") for (int r = 0; r < 4; ++r){ int d = (ti/3)*16 + quad*4 + r, e = (ti%3)*16 + lrow; F[d*48 + e] = acc[ti][r]; } } }
  #define ADDF(W) if (wave == (W)){ _Pragma("unroll") for (int ti = 0; ti < 9; ++ti){ _Pragma("unroll") for (int r = 0; r < 4; ++r){ int d = (ti/3)*16 + quad*4 + r, e = (ti%3)*16 + lrow; acc[ti][r] += F[d*48 + e]; } } }
  DUMP(1) __syncthreads(); ADDF(0) __syncthreads();
  DUMP(3) __syncthreads(); ADDF(2) __syncthreads();
  DUMP(2) __syncthreads(); ADDF(0) __syncthreads();
  #undef DUMP
  #undef ADDF
  if (wave == 0){
    #pragma unroll
    for (int ti = 0; ti < 9; ++ti){
      #pragma unroll
      for (int r = 0; r < 4; ++r){
        int d = (ti/3)*16 + quad*4 + r, e = (ti%3)*16 + lrow;
        atomicAdd(&kvT_out[(size_t)bh*2304 + e*48 + d], acc[ti][r]);
      }
    }
  }
  if (wave == 3 && lane < 48) atomicAdd(&ksum_out[bh*48 + lane], ks);
}

// ---------------- attn via MFMA: out[n,e] = (q[n,:] @ kv*temp)[e] / max(q[n,:].ksum, 100) ----------------
// B-operand in LDS: cols 0-47 = kvT*temp, col 48 = ksum, cols 49-63 = 0; K rows 48-63 = 0
// grid (256 bh, 13 token-chunks of 256); block 256 = 4 waves x 64 tokens
__global__ __launch_bounds__(256)
void attn_mfma_kernel(const ushort_t* __restrict__ qkv, const float* __restrict__ kvT,
                      const float* __restrict__ ksum, const float* __restrict__ temp,
                      ushort_t* __restrict__ attn_out){
  __shared__ __align__(16) ushort_t Bs[64*72];
  int bh = blockIdx.x, b = bh >> 3, h = bh & 7;
  int t = threadIdx.x, lane = t & 63, wave = t >> 6;
  int lrow = lane & 15, quad = lane >> 4;
  float tf = temp[h];
  for (int u = t; u < 64*72; u += 256){
    int col = u / 72, d = u - col*72;
    float v = 0.f;
    if (d < 48){
      if (col < 48) v = kvT[(size_t)bh*2304 + col*48 + d] * tf;
      else if (col == 48) v = ksum[bh*48 + d];
    }
    Bs[u] = f2bf(v);
  }
  __syncthreads();
  short8 bfv[4][2];
  #pragma unroll
  for (int j = 0; j < 4; ++j)
    #pragma unroll
    for (int s = 0; s < 2; ++s)
      bfv[j][s] = *(const short8*)&Bs[(j*16 + lrow)*72 + s*32 + quad*8];

  const ushort_t* qb = qkv + (size_t)b*NN*1152 + h*48;
  int n0 = blockIdx.y*256 + wave*64;
  floatx4 acc[4][4];
  #pragma unroll
  for (int i = 0; i < 4; ++i)
    #pragma unroll
    for (int j = 0; j < 4; ++j) acc[i][j] = (floatx4){0.f,0.f,0.f,0.f};

  #pragma unroll
  for (int i = 0; i < 4; ++i){
    int nrow = n0 + i*16 + lrow;     // may exceed NN for last block; reads stay in-buffer, stores guarded
    #pragma unroll
    for (int s = 0; s < 2; ++s){
      short8 af = *(const short8*)&qb[(size_t)nrow*1152 + s*32 + quad*8];
      #pragma unroll
      for (int j = 0; j < 4; ++j)
        acc[i][j] = __builtin_amdgcn_mfma_f32_16x16x32_bf16(af, bfv[j][s], acc[i][j], 0, 0, 0);
    }
  }

  ushort_t* ob = attn_out + (size_t)b*NN*BDIM + h*48;
  #pragma unroll
  for (int i = 0; i < 4; ++i){
    #pragma unroll
    for (int r = 0; r < 4; ++r){
      float den = __shfl(acc[i][3][r], quad*16);   // col 48 = q.ksum for row quad*4+r
      den = fmaxf(den, 100.f);
      int nrow = n0 + i*16 + quad*4 + r;
      if (nrow < NN){
        #pragma unroll
        for (int j = 0; j < 3; ++j)
          ob[(size_t)nrow*BDIM + j*16 + lrow] = f2bf(acc[i][j][r] / den);
      }
    }
  }
}

extern "C" void kernel_launch(void* const* d_in, const int* in_sizes, int n_in,
                              void* d_out, int out_size, void* d_ws, size_t ws_size,
                              hipStream_t stream){
  const float* x     = (const float*)d_in[0];
  const float* cpe_w = (const float*)d_in[3];
  const float* cpe_b = (const float*)d_in[4];
  const float* ln1_w = (const float*)d_in[5];
  const float* ln1_b = (const float*)d_in[6];
  const float* qkv_w = (const float*)d_in[7];
  const float* qkv_b = (const float*)d_in[8];
  const float* temp  = (const float*)d_in[9];
  const float* proj_w= (const float*)d_in[10];
  const float* proj_b= (const float*)d_in[11];
  const float* ln2_w = (const float*)d_in[12];
  const float* ln2_b = (const float*)d_in[13];
  const float* fc1_w = (const float*)d_in[14];
  const float* fc1_b = (const float*)d_in[15];
  const float* fc2_w = (const float*)d_in[16];
  const float* fc2_b = (const float*)d_in[17];
  float* out = (float*)d_out;

  char* ws = (char*)d_ws;
  size_t off = 0;
  auto alloc = [&](size_t bytes) -> void* {
    void* p = ws + off;
    off += (bytes + 255) & ~(size_t)255;
    return p;
  };
  ushort_t* cur  = (ushort_t*)alloc((size_t)MTOT*BDIM*2);
  ushort_t* big  = (ushort_t*)alloc((size_t)MTOT*HID*2);
  float*    kvT  = (float*)   alloc((size_t)BB*HEADS*HD*HD*4);
  float*    ksum = (float*)   alloc((size_t)BB*HEADS*HD*4);
  ushort_t* wq = (ushort_t*)alloc((size_t)3*BDIM*BDIM*2);
  ushort_t* wp = (ushort_t*)alloc((size_t)BDIM*BDIM*2);
  ushort_t* w1 = (ushort_t*)alloc((size_t)HID*BDIM*2);
  ushort_t* w2 = (ushort_t*)alloc((size_t)BDIM*HID*2);

  convert_bf16_kernel<<<(3*BDIM*BDIM + 255)/256, 256, 0, stream>>>(qkv_w, wq, 3*BDIM*BDIM);
  convert_bf16_kernel<<<(BDIM*BDIM + 255)/256, 256, 0, stream>>>(proj_w, wp, BDIM*BDIM);
  convert_bf16_kernel<<<(HID*BDIM + 255)/256, 256, 0, stream>>>(fc1_w, w1, HID*BDIM);
  convert_bf16_kernel<<<(BDIM*HID + 255)/256, 256, 0, stream>>>(fc2_w, w2, BDIM*HID);

  hipMemsetAsync(kvT, 0, (size_t)BB*HEADS*HD*HD*4, stream);
  hipMemsetAsync(ksum, 0, (size_t)BB*HEADS*HD*4, stream);

  cpe_ln1_kernel<<<MTOT, 384, 0, stream>>>(x, cpe_w, cpe_b, ln1_w, ln1_b, out, cur);
  gemm_kernel<0><<<dim3(9, 784), 256, 0, stream>>>(cur, wq, qkv_b, nullptr, big, 1152, BDIM);
  kv_mfma_kernel<<<dim3(BB*HEADS, 7), 256, 0, stream>>>(big, kvT, ksum);
  attn_mfma_kernel<<<dim3(BB*HEADS, 13), 256, 0, stream>>>(big, kvT, ksum, temp, cur);
  gemm_kernel<2><<<dim3(3, 784), 256, 0, stream>>>(cur, wp, proj_b, out, out, BDIM, BDIM);
  ln_kernel<<<MTOT, 384, 0, stream>>>(out, ln2_w, ln2_b, cur);
  gemm_kernel<1><<<dim3(12, 784), 256, 0, stream>>>(cur, w1, fc1_b, nullptr, big, HID, BDIM);
  gemm_kernel<2><<<dim3(3, 784), 256, 0, stream>>>(big, w2, fc2_b, out, out, BDIM, HID);
}

// Round 3
// 1517.584 us; speedup vs baseline: 1.8912x; 1.1340x over previous
//
#include <hip/hip_runtime.h>
#include <hip/hip_bf16.h>
#include <math.h>

#define BDIM 384
#define HEADS 8
#define HD 48
#define HID 1536
#define BB 32
#define HH 56
#define WW 56
#define NN 3136            // 56*56
#define MTOT (BB*NN)       // 100352
#define TPW 8              // tokens per wave in cpe/ln kernels

typedef unsigned short ushort_t;
typedef __attribute__((ext_vector_type(8))) short short8;   // 8 x bf16 (4 VGPRs)
typedef __attribute__((ext_vector_type(4))) float floatx4;  // 4 x f32 acc

__device__ inline float bf2f(ushort_t u){ return __uint_as_float(((unsigned)u)<<16); }
__device__ inline ushort_t f2bf(float f){
  unsigned u = __float_as_uint(f);
  u += 0x7fff + ((u>>16)&1);   // round-to-nearest-even
  return (ushort_t)(u>>16);
}

// async global->LDS, 16B per lane; lds dest = wave-uniform base + lane*16
__device__ inline void async_ld16(const void* g, void* l){
  __builtin_amdgcn_global_load_lds((const __attribute__((address_space(1))) void*)g,
                                   (__attribute__((address_space(3))) void*)l, 16, 0, 0);
}

// ---------------- weight fp32 -> bf16 ----------------
__global__ void convert_bf16_kernel(const float* __restrict__ in, ushort_t* __restrict__ out, int n){
  int i = blockIdx.x*256 + threadIdx.x;
  if (i < n) out[i] = f2bf(in[i]);
}

// ---------------- CPE depthwise 3x3 conv + residual + LN1 (wave-per-token, no barriers) ----------------
// block 256 = 4 waves; each wave does TPW consecutive tokens; lane owns channels p*64+lane
__global__ __launch_bounds__(256)
void cpe_ln1_kernel(const float* __restrict__ x, const float* __restrict__ cw,
                    const float* __restrict__ cb, const float* __restrict__ lw,
                    const float* __restrict__ lb, float* __restrict__ x1out,
                    ushort_t* __restrict__ cur){
  int lane = threadIdx.x & 63, wave = threadIdx.x >> 6;
  size_t base = ((size_t)blockIdx.x*4 + wave) * TPW;
  float wreg[6][9], cbr[6], lwr[6], lbr[6];
  #pragma unroll
  for (int p = 0; p < 6; ++p){
    int c = p*64 + lane;
    cbr[p] = cb[c]; lwr[p] = lw[c]; lbr[p] = lb[c];
    #pragma unroll
    for (int j = 0; j < 9; ++j) wreg[p][j] = cw[c*9+j];
  }
  for (int ti = 0; ti < TPW; ++ti){
    size_t bn = base + ti;
    int b = (int)(bn / NN), n = (int)(bn % NN);
    int h = n / WW, w = n % WW;
    const float* xb = x + ((size_t)b*NN)*BDIM;
    float conv[6];
    #pragma unroll
    for (int p = 0; p < 6; ++p) conv[p] = cbr[p];
    #pragma unroll
    for (int dh = -1; dh <= 1; ++dh){
      int hh = h + dh; if ((unsigned)hh >= HH) continue;
      #pragma unroll
      for (int dw = -1; dw <= 1; ++dw){
        int w2 = w + dw; if ((unsigned)w2 >= WW) continue;
        const float* src = xb + (size_t)(hh*WW + w2)*BDIM + lane;
        int j = (dh+1)*3 + (dw+1);
        #pragma unroll
        for (int p = 0; p < 6; ++p) conv[p] += src[p*64] * wreg[p][j];
      }
    }
    const float* xc = xb + (size_t)n*BDIM + lane;
    float x1[6], s = 0.f, q = 0.f;
    #pragma unroll
    for (int p = 0; p < 6; ++p){
      x1[p] = xc[p*64] + conv[p];
      s += x1[p]; q += x1[p]*x1[p];
    }
    #pragma unroll
    for (int off = 32; off; off >>= 1){
      s += __shfl_xor(s, off);
      q += __shfl_xor(q, off);
    }
    float mean = s*(1.f/384.f);
    float rstd = rsqrtf(q*(1.f/384.f) - mean*mean + 1e-5f);
    float* xo = x1out + bn*BDIM + lane;
    ushort_t* co = cur + bn*BDIM + lane;
    #pragma unroll
    for (int p = 0; p < 6; ++p){
      xo[p*64] = x1[p];
      co[p*64] = f2bf((x1[p]-mean)*rstd*lwr[p] + lbr[p]);
    }
  }
}

// ---------------- plain LN (wave-per-token, no barriers) ----------------
__global__ __launch_bounds__(256)
void ln_kernel(const float* __restrict__ xin, const float* __restrict__ lw,
               const float* __restrict__ lb, ushort_t* __restrict__ outb){
  int lane = threadIdx.x & 63, wave = threadIdx.x >> 6;
  size_t base = ((size_t)blockIdx.x*4 + wave) * TPW;
  float lwr[6], lbr[6];
  #pragma unroll
  for (int p = 0; p < 6; ++p){ lwr[p] = lw[p*64+lane]; lbr[p] = lb[p*64+lane]; }
  for (int ti = 0; ti < TPW; ++ti){
    size_t bn = base + ti;
    const float* xi = xin + bn*BDIM + lane;
    float v[6], s = 0.f, q = 0.f;
    #pragma unroll
    for (int p = 0; p < 6; ++p){
      v[p] = xi[p*64];
      s += v[p]; q += v[p]*v[p];
    }
    #pragma unroll
    for (int off = 32; off; off >>= 1){
      s += __shfl_xor(s, off);
      q += __shfl_xor(q, off);
    }
    float mean = s*(1.f/384.f);
    float rstd = rsqrtf(q*(1.f/384.f) - mean*mean + 1e-5f);
    ushort_t* oo = outb + bn*BDIM + lane;
    #pragma unroll
    for (int p = 0; p < 6; ++p) oo[p*64] = f2bf((v[p]-mean)*rstd*lwr[p] + lbr[p]);
  }
}

// ---------------- bf16 MFMA GEMM with async global->LDS staging ----------------
// BM=BN=128, BK=32; 256 threads = 4 waves in 2x2; each wave: 4x4 tiles of 16x16
template<int EP>
__global__ __launch_bounds__(256)
void gemm_kernel(const ushort_t* __restrict__ A, const ushort_t* __restrict__ Bw,
                 const float* __restrict__ bias, const float* __restrict__ resid,
                 void* __restrict__ outp, int Ncols, int K){
  __shared__ __align__(16) ushort_t As[128*32];
  __shared__ __align__(16) ushort_t Bs[128*32];
  const int t = threadIdx.x;
  const int lane = t & 63, wave = t >> 6;
  const int wm = wave >> 1, wn = wave & 1;
  const size_t m0 = (size_t)blockIdx.y * 128;
  const int n0 = blockIdx.x * 128;
  const int lrow = lane & 15, lk = (lane >> 4) << 3;
  floatx4 zero4 = {0.f, 0.f, 0.f, 0.f};
  floatx4 acc[4][4];
  #pragma unroll
  for (int i = 0; i < 4; ++i)
    #pragma unroll
    for (int j = 0; j < 4; ++j) acc[i][j] = zero4;

  for (int k0 = 0; k0 < K; k0 += 32){
    #pragma unroll
    for (int l = 0; l < 2; ++l){
      int idx = t + l*256;              // 0..511
      int row = idx >> 2;               // 0..127
      int ko  = (idx & 3) << 3;         // 0,8,16,24
      int lbase = (l*256 + wave*64) * 8;  // wave-uniform LDS elem base; lane lands at +lane*8
      async_ld16(&A[(m0 + row)*K + (k0 + ko)], &As[lbase]);
      async_ld16(&Bw[(size_t)(n0 + row)*K + (k0 + ko)], &Bs[lbase]);
    }
    __syncthreads();
    short8 af[4], bfr[4];
    #pragma unroll
    for (int i = 0; i < 4; ++i) af[i]  = *(const short8*)&As[(wm*64 + i*16 + lrow)*32 + lk];
    #pragma unroll
    for (int j = 0; j < 4; ++j) bfr[j] = *(const short8*)&Bs[(wn*64 + j*16 + lrow)*32 + lk];
    #pragma unroll
    for (int i = 0; i < 4; ++i)
      #pragma unroll
      for (int j = 0; j < 4; ++j)
        acc[i][j] = __builtin_amdgcn_mfma_f32_16x16x32_bf16(af[i], bfr[j], acc[i][j], 0, 0, 0);
    __syncthreads();
  }

  const int quad = lane >> 4;
  #pragma unroll
  for (int i = 0; i < 4; ++i){
    #pragma unroll
    for (int j = 0; j < 4; ++j){
      int gn = n0 + wn*64 + j*16 + lrow;
      float bv = bias[gn];
      #pragma unroll
      for (int r = 0; r < 4; ++r){
        size_t gm = m0 + wm*64 + i*16 + quad*4 + r;
        float v = acc[i][j][r] + bv;
        if constexpr (EP == 0){
          if (gn < 768) v = fmaxf(v, 0.f);
          ((ushort_t*)outp)[gm*Ncols + gn] = f2bf(v);
        } else if constexpr (EP == 1){
          v = 0.5f*v*(1.f + erff(v*0.70710678118f));
          ((ushort_t*)outp)[gm*Ncols + gn] = f2bf(v);
        } else {
          ((float*)outp)[gm*Ncols + gn] = v + resid[gm*Ncols + gn];
        }
      }
    }
  }
}

// ---------------- kv via MFMA (unchanged from R2) ----------------
__global__ __launch_bounds__(256)
void kv_mfma_kernel(const ushort_t* __restrict__ qkv, float* __restrict__ kvT_out,
                    float* __restrict__ ksum_out){
  __shared__ __align__(16) ushort_t smem[2*48*72];   // kT [48][72], vT [48][72]
  ushort_t* kT = smem;
  ushort_t* vT = smem + 48*72;
  int bh = blockIdx.x, b = bh >> 3, h = bh & 7;
  int chunk = blockIdx.y;
  int t = threadIdx.x, lane = t & 63, wave = t >> 6;
  int lrow = lane & 15, quad = lane >> 4;
  const ushort_t* kb = qkv + (size_t)b*NN*1152 + 384 + h*48;
  const ushort_t* vb = kb + 384;
  floatx4 acc[9];
  #pragma unroll
  for (int i = 0; i < 9; ++i) acc[i] = (floatx4){0.f,0.f,0.f,0.f};
  float ks = 0.f;

  for (int s = 0; s < 7; ++s){
    int n0 = chunk*448 + s*64;
    #pragma unroll
    for (int p = 0; p < 3; ++p){
      int u = t + p*256;              // 0..767
      int arr = u / 384;              // 0=k, 1=v
      int r = u - arr*384;
      int d8 = r >> 6;                // 0..5
      int nl = r & 63;
      const ushort_t* src = (arr ? vb : kb) + (size_t)(n0 + nl)*1152 + d8*8;
      ushort_t* dst = arr ? vT : kT;
      uint4 val = *(const uint4*)src;
      ushort_t tmp[8];
      *(uint4*)tmp = val;
      #pragma unroll
      for (int j = 0; j < 8; ++j) dst[(d8*8 + j)*72 + nl] = tmp[j];
    }
    __syncthreads();
    if ((wave >> 1) == (s & 1)){
      int kloc = (wave & 1) * 32;
      short8 af[3], bfv[3];
      #pragma unroll
      for (int i = 0; i < 3; ++i) af[i]  = *(const short8*)&kT[(i*16 + lrow)*72 + kloc + quad*8];
      #pragma unroll
      for (int j = 0; j < 3; ++j) bfv[j] = *(const short8*)&vT[(j*16 + lrow)*72 + kloc + quad*8];
      #pragma unroll
      for (int i = 0; i < 3; ++i)
        #pragma unroll
        for (int j = 0; j < 3; ++j)
          acc[i*3+j] = __builtin_amdgcn_mfma_f32_16x16x32_bf16(af[i], bfv[j], acc[i*3+j], 0, 0, 0);
    }
    if (wave == 3 && lane < 48){
      float s2 = 0.f;
      #pragma unroll
      for (int q8 = 0; q8 < 8; ++q8){
        short8 kk = *(const short8*)&kT[lane*72 + q8*8];
        #pragma unroll
        for (int j = 0; j < 8; ++j) s2 += bf2f((ushort_t)kk[j]);
      }
      ks += s2;
    }
    __syncthreads();
  }

  float* F = (float*)smem;
  #define DUMP(W) if (wave == (W)){ _Pragma("unroll") for (int ti = 0; ti < 9; ++ti){ _Pragma("unroll") for (int r = 0; r < 4; ++r){ int d = (ti/3)*16 + quad*4 + r, e = (ti%3)*16 + lrow; F[d*48 + e] = acc[ti][r]; } } }
  #define ADDF(W) if (wave == (W)){ _Pragma("unroll") for (int ti = 0; ti < 9; ++ti){ _Pragma("unroll") for (int r = 0; r < 4; ++r){ int d = (ti/3)*16 + quad*4 + r, e = (ti%3)*16 + lrow; acc[ti][r] += F[d*48 + e]; } } }
  DUMP(1) __syncthreads(); ADDF(0) __syncthreads();
  DUMP(3) __syncthreads(); ADDF(2) __syncthreads();
  DUMP(2) __syncthreads(); ADDF(0) __syncthreads();
  #undef DUMP
  #undef ADDF
  if (wave == 0){
    #pragma unroll
    for (int ti = 0; ti < 9; ++ti){
      #pragma unroll
      for (int r = 0; r < 4; ++r){
        int d = (ti/3)*16 + quad*4 + r, e = (ti%3)*16 + lrow;
        atomicAdd(&kvT_out[(size_t)bh*2304 + e*48 + d], acc[ti][r]);
      }
    }
  }
  if (wave == 3 && lane < 48) atomicAdd(&ksum_out[bh*48 + lane], ks);
}

// ---------------- attn via MFMA (unchanged from R2) ----------------
__global__ __launch_bounds__(256)
void attn_mfma_kernel(const ushort_t* __restrict__ qkv, const float* __restrict__ kvT,
                      const float* __restrict__ ksum, const float* __restrict__ temp,
                      ushort_t* __restrict__ attn_out){
  __shared__ __align__(16) ushort_t Bs[64*72];
  int bh = blockIdx.x, b = bh >> 3, h = bh & 7;
  int t = threadIdx.x, lane = t & 63, wave = t >> 6;
  int lrow = lane & 15, quad = lane >> 4;
  float tf = temp[h];
  for (int u = t; u < 64*72; u += 256){
    int col = u / 72, d = u - col*72;
    float v = 0.f;
    if (d < 48){
      if (col < 48) v = kvT[(size_t)bh*2304 + col*48 + d] * tf;
      else if (col == 48) v = ksum[bh*48 + d];
    }
    Bs[u] = f2bf(v);
  }
  __syncthreads();
  short8 bfv[4][2];
  #pragma unroll
  for (int j = 0; j < 4; ++j)
    #pragma unroll
    for (int s = 0; s < 2; ++s)
      bfv[j][s] = *(const short8*)&Bs[(j*16 + lrow)*72 + s*32 + quad*8];

  const ushort_t* qb = qkv + (size_t)b*NN*1152 + h*48;
  int n0 = blockIdx.y*256 + wave*64;
  floatx4 acc[4][4];
  #pragma unroll
  for (int i = 0; i < 4; ++i)
    #pragma unroll
    for (int j = 0; j < 4; ++j) acc[i][j] = (floatx4){0.f,0.f,0.f,0.f};

  #pragma unroll
  for (int i = 0; i < 4; ++i){
    int nrow = n0 + i*16 + lrow;
    #pragma unroll
    for (int s = 0; s < 2; ++s){
      short8 af = *(const short8*)&qb[(size_t)nrow*1152 + s*32 + quad*8];
      #pragma unroll
      for (int j = 0; j < 4; ++j)
        acc[i][j] = __builtin_amdgcn_mfma_f32_16x16x32_bf16(af, bfv[j][s], acc[i][j], 0, 0, 0);
    }
  }

  ushort_t* ob = attn_out + (size_t)b*NN*BDIM + h*48;
  #pragma unroll
  for (int i = 0; i < 4; ++i){
    #pragma unroll
    for (int r = 0; r < 4; ++r){
      float den = __shfl(acc[i][3][r], quad*16);
      den = fmaxf(den, 100.f);
      int nrow = n0 + i*16 + quad*4 + r;
      if (nrow < NN){
        #pragma unroll
        for (int j = 0; j < 3; ++j)
          ob[(size_t)nrow*BDIM + j*16 + lrow] = f2bf(acc[i][j][r] / den);
      }
    }
  }
}

extern "C" void kernel_launch(void* const* d_in, const int* in_sizes, int n_in,
                              void* d_out, int out_size, void* d_ws, size_t ws_size,
                              hipStream_t stream){
  const float* x     = (const float*)d_in[0];
  const float* cpe_w = (const float*)d_in[3];
  const float* cpe_b = (const float*)d_in[4];
  const float* ln1_w = (const float*)d_in[5];
  const float* ln1_b = (const float*)d_in[6];
  const float* qkv_w = (const float*)d_in[7];
  const float* qkv_b = (const float*)d_in[8];
  const float* temp  = (const float*)d_in[9];
  const float* proj_w= (const float*)d_in[10];
  const float* proj_b= (const float*)d_in[11];
  const float* ln2_w = (const float*)d_in[12];
  const float* ln2_b = (const float*)d_in[13];
  const float* fc1_w = (const float*)d_in[14];
  const float* fc1_b = (const float*)d_in[15];
  const float* fc2_w = (const float*)d_in[16];
  const float* fc2_b = (const float*)d_in[17];
  float* out = (float*)d_out;

  char* ws = (char*)d_ws;
  size_t off = 0;
  auto alloc = [&](size_t bytes) -> void* {
    void* p = ws + off;
    off += (bytes + 255) & ~(size_t)255;
    return p;
  };
  ushort_t* cur  = (ushort_t*)alloc((size_t)MTOT*BDIM*2);
  ushort_t* big  = (ushort_t*)alloc((size_t)MTOT*HID*2);
  float*    kvT  = (float*)   alloc((size_t)BB*HEADS*HD*HD*4);
  float*    ksum = (float*)   alloc((size_t)BB*HEADS*HD*4);
  ushort_t* wq = (ushort_t*)alloc((size_t)3*BDIM*BDIM*2);
  ushort_t* wp = (ushort_t*)alloc((size_t)BDIM*BDIM*2);
  ushort_t* w1 = (ushort_t*)alloc((size_t)HID*BDIM*2);
  ushort_t* w2 = (ushort_t*)alloc((size_t)BDIM*HID*2);

  convert_bf16_kernel<<<(3*BDIM*BDIM + 255)/256, 256, 0, stream>>>(qkv_w, wq, 3*BDIM*BDIM);
  convert_bf16_kernel<<<(BDIM*BDIM + 255)/256, 256, 0, stream>>>(proj_w, wp, BDIM*BDIM);
  convert_bf16_kernel<<<(HID*BDIM + 255)/256, 256, 0, stream>>>(fc1_w, w1, HID*BDIM);
  convert_bf16_kernel<<<(BDIM*HID + 255)/256, 256, 0, stream>>>(fc2_w, w2, BDIM*HID);

  hipMemsetAsync(kvT, 0, (size_t)BB*HEADS*HD*HD*4, stream);
  hipMemsetAsync(ksum, 0, (size_t)BB*HEADS*HD*4, stream);

  cpe_ln1_kernel<<<MTOT/(4*TPW), 256, 0, stream>>>(x, cpe_w, cpe_b, ln1_w, ln1_b, out, cur);
  gemm_kernel<0><<<dim3(9, 784), 256, 0, stream>>>(cur, wq, qkv_b, nullptr, big, 1152, BDIM);
  kv_mfma_kernel<<<dim3(BB*HEADS, 7), 256, 0, stream>>>(big, kvT, ksum);
  attn_mfma_kernel<<<dim3(BB*HEADS, 13), 256, 0, stream>>>(big, kvT, ksum, temp, cur);
  gemm_kernel<2><<<dim3(3, 784), 256, 0, stream>>>(cur, wp, proj_b, out, out, BDIM, BDIM);
  ln_kernel<<<MTOT/(4*TPW), 256, 0, stream>>>(out, ln2_w, ln2_b, cur);
  gemm_kernel<1><<<dim3(12, 784), 256, 0, stream>>>(cur, w1, fc1_b, nullptr, big, HID, BDIM);
  gemm_kernel<2><<<dim3(3, 784), 256, 0, stream>>>(big, w2, fc2_b, out, out, BDIM, HID);
}